// Round 1
// baseline (233.494 us; speedup 1.0000x reference)
//
#include <hip/hip_runtime.h>

#define N_PTS  20000
#define NG     128                  // grid NG x NG over [-6,6]^2
#define NC     (NG * NG)            // 16384 cells per cloud
#define GMIN   (-6.0f)
#define GINV   (NG / 12.0f)
#define MARGIN 5e-4f                // >> 2e-5 worst-case |P_np - d_true^2|
#define QB79   79                   // fallback

// ---- numpy-exact helpers (proven rounds 2/5/9/10/11/14) ----
__device__ __forceinline__ float np_self_dot(float x, float y, float z) {
    return __fadd_rn(__fadd_rn(__fmul_rn(x, x), __fmul_rn(y, y)),
                     __fmul_rn(z, z));
}
__device__ __forceinline__ unsigned ordmap(float f) {
    unsigned b = __float_as_uint(f);
    return (b & 0x80000000u) ? ~b : (b | 0x80000000u);
}
__device__ __forceinline__ float invord(unsigned h) {
    return __uint_as_float((h & 0x80000000u) ? (h ^ 0x80000000u) : ~h);
}
__device__ __forceinline__ int cellC(float v) {
    int c = (int)((v - GMIN) * GINV);
    return c < 0 ? 0 : (c > NG - 1 ? NG - 1 : c);
}
// min over an aligned 16-lane subgroup (masks 1,2,4,8 stay inside group)
__device__ __forceinline__ unsigned long long grp16_min_u64(unsigned long long k) {
    #pragma unroll
    for (int m = 1; m < 16; m <<= 1) {
        unsigned long long o = __shfl_xor(k, m, 64);
        k = (o < k) ? o : k;
    }
    return k;
}

// ---- build A1 (r16): wide parallel histogram via global atomics ----
// cursor[] doubles as the histogram buffer (zeroed by hipMemsetAsync).
__global__ __launch_bounds__(256) void k_hist(
    const float* __restrict__ preds, const float* __restrict__ gts,
    int* __restrict__ cursor)
{
    int t = blockIdx.x * 256 + threadIdx.x;
    if (t >= 2 * N_PTS) return;
    int cl = t / N_PTS, i = t - cl * N_PTS;
    const float* src = cl ? gts : preds;
    int cell = cellC(src[i*3+0]) * NG + cellC(src[i*3+1]);
    atomicAdd(&cursor[cl * NC + cell], 1);
}

// ---- build A2 (r16): scan-only, 1 block/cloud (scan was never the cost) ----
// Reads counts from cursor, rewrites cursor to run starts. Safe: every
// thread's 16 reads complete before the first __syncthreads of the scan.
__global__ __launch_bounds__(1024) void k_scan(
    int* __restrict__ cursor, int* __restrict__ bstart)
{
    __shared__ int psum[1024];      // 4 KB
    int cl = blockIdx.x, t = threadIdx.x;

    int base = t * 16;
    int v[16], s = 0;
    #pragma unroll
    for (int i = 0; i < 16; ++i) { v[i] = cursor[cl * NC + base + i]; s += v[i]; }
    psum[t] = s;
    __syncthreads();
    for (int off = 1; off < 1024; off <<= 1) {     // Hillis-Steele inclusive
        int a = (t >= off) ? psum[t - off] : 0;
        __syncthreads();
        psum[t] += a;
        __syncthreads();
    }
    int run = psum[t] - s;                          // exclusive prefix
    #pragma unroll
    for (int i = 0; i < 16; ++i) {
        bstart[cl * (NC + 1) + base + i] = run;
        cursor[cl * NC + base + i] = run;
        run += v[i];
    }
    if (t == 1023) bstart[cl * (NC + 1) + NC] = run;   // == N_PTS
}

// ---- build B (r15): wide scatter (157 blocks) into cell-sorted order ----
// Record = {x, y, z, bitcast(orig_idx)} (r14's proven layout).
__global__ __launch_bounds__(256) void k_scatter(
    const float* __restrict__ preds, const float* __restrict__ gts,
    int* __restrict__ cursor, float4* __restrict__ sorted)
{
    int t = blockIdx.x * 256 + threadIdx.x;
    if (t >= 2 * N_PTS) return;
    int cl = t / N_PTS, i = t - cl * N_PTS;
    const float* src = cl ? gts : preds;
    float x = src[i*3+0], y = src[i*3+1], z = src[i*3+2];
    int cell = cellC(x) * NG + cellC(y);
    int pos = atomicAdd(&cursor[cl * NC + cell], 1);
    sorted[(size_t)cl * N_PTS + pos] = make_float4(x, y, z, __int_as_float(i));
}

// ---- main (r16): 16-lane subgroup per query — 4 adjacent (cell-sorted,
// hence coherent) queries per wave. Same algorithm/numerics as r9-r15:
// numpy-exact P; key=(ordmap(P)<<32|idx); subgroup-min == numpy
// first-occurrence argmin; MARGIN-pruning strict-safe. Candidate coverage
// per query identical (stride-16 lanes cover [lo,hi) fully; rescans
// idempotent). Rationale: rows average 4-84 points, so 64-lane scanning
// ran 75-95% lanes dead (VALUBusy 31%, HBM 0.7% => lane-waste-bound).
__global__ __launch_bounds__(256) void k_main(
    const float4* __restrict__ sorted, const int* __restrict__ bstart,
    float* __restrict__ out)
{
    int wave = blockIdx.x * 4 + ((int)threadIdx.x >> 6);   // 0..9999
    int sub  = ((int)threadIdx.x >> 4) & 3;                // subgroup in wave
    int lane = threadIdx.x & 15;
    int wid  = wave * 4 + sub;                             // query 0..39999
    int dir  = wid / N_PTS;
    int qpos = wid - dir * N_PTS;
    int rcl  = 1 - dir;

    const float4* rs = sorted + (size_t)rcl * N_PTS;
    const int*    cs = bstart + rcl * (NC + 1);

    float4 qv    = sorted[(size_t)dir * N_PTS + qpos];     // subgroup-broadcast
    int    origq = __float_as_int(qv.w);
    float qx = qv.x, qy = qv.y, qz = qv.z;
    float sq = np_self_dot(qx, qy, qz);

    unsigned long long key = ~0ULL;

#define EVAL(r)                                                            \
    {   float sr = np_self_dot((r).x, (r).y, (r).z);                       \
        float zz = __fadd_rn(__fadd_rn(__fmul_rn(qx, (r).x),               \
                                       __fmul_rn(qy, (r).y)),              \
                             __fmul_rn(qz, (r).z));                        \
        float P  = __fsub_rn(__fadd_rn(sq, sr), __fadd_rn(zz, zz));        \
        unsigned long long kk =                                            \
            ((unsigned long long)ordmap(P) << 32) | __float_as_uint((r).w);\
        key = (kk < key) ? kk : key; }

#define ROW(x, ya, yb)                                                     \
    if ((yb) >= (ya)) {                                                    \
        int lo = cs[(x) * NG + (ya)], hi = cs[(x) * NG + (yb) + 1];        \
        int p = lo + lane;                                                 \
        for (; p + 16 < hi; p += 32) {                                     \
            float4 r0 = rs[p];                                             \
            float4 r1 = rs[p + 16];       /* 2 loads in flight */          \
            EVAL(r0) EVAL(r1)                                              \
        }                                                                  \
        if (p < hi) { float4 r0 = rs[p]; EVAL(r0) }                        \
    }

    int cx = cellC(qx), cy = cellC(qy);
    int sxL = cx > 0 ? cx - 1 : 0, sxR = cx < NG-1 ? cx + 1 : NG-1;
    int syL = cy > 0 ? cy - 1 : 0, syR = cy < NG-1 ? cy + 1 : NG-1;

    for (int x = sxL; x <= sxR; ++x) ROW(x, syL, syR)      // seed 3x3

    for (int round = 0; round < 24; ++round) {
        key = grp16_min_u64(key);
        int txL, txR, tyL, tyR;
        if (key != ~0ULL) {
            float W = sqrtf(invord((unsigned)(key >> 32)) + MARGIN);
            txL = cellC(qx - W); txR = cellC(qx + W);
            tyL = cellC(qy - W); tyR = cellC(qy + W);
        } else {                                           // empty seed: grow
            int gx = sxR - sxL + 1, gy = syR - syL + 1;
            txL = sxL - gx; txR = sxR + gx;
            tyL = syL - gy; tyR = syR + gy;
            txL = txL < 0 ? 0 : txL;  tyL = tyL < 0 ? 0 : tyL;
            txR = txR > NG-1 ? NG-1 : txR;
            tyR = tyR > NG-1 ? NG-1 : tyR;
        }
        if (txL >= sxL && txR <= sxR && tyL >= syL && tyR <= syR) break;
        for (int x = txL; x <= txR; ++x) {
            if (x >= sxL && x <= sxR) {                    // new strips only
                ROW(x, tyL, syL - 1)
                ROW(x, syR + 1, tyR)
            } else {
                ROW(x, tyL, tyR)
            }
        }
        sxL = txL; sxR = txR; syL = tyL; syR = tyR;
    }
#undef ROW
#undef EVAL

    key = grp16_min_u64(key);
    if (lane == 0) {
        out[dir * N_PTS + origq]       = invord((unsigned)(key >> 32));
        out[(2 + dir) * N_PTS + origq] = (float)(unsigned)(key & 0xFFFFFFFFu);
    }
}

// ---- fallback (tiny workspace): brute-force direct kernel (proven r2) ----
__device__ __forceinline__ float np_pair(float sq, float sr,
                                         float qx, float qy, float qz,
                                         float rx, float ry, float rz) {
    float zz = __fadd_rn(__fadd_rn(__fmul_rn(qx, rx), __fmul_rn(qy, ry)),
                         __fmul_rn(qz, rz));
    return __fsub_rn(__fadd_rn(sq, sr), __fadd_rn(zz, zz));
}

__global__ __launch_bounds__(256) void chamfer_direct_kernel(
    const float* __restrict__ preds, const float* __restrict__ gts,
    float* __restrict__ out)
{
    __shared__ float4 spts[256];
    int bid = blockIdx.x;
    int dir = bid / QB79;
    int qb  = bid - dir * QB79;
    int q   = qb * 256 + threadIdx.x;

    const float* qpts = (dir == 0) ? preds : gts;
    const float* rpts = (dir == 0) ? gts   : preds;

    int qc = (q < N_PTS) ? q : (N_PTS - 1);
    float qx = qpts[qc*3+0], qy = qpts[qc*3+1], qz = qpts[qc*3+2];
    float sq = np_self_dot(qx, qy, qz);
    float best = 3.4e38f;
    int   bidx = 0;

    for (int t = 0; t < N_PTS; t += 256) {
        int cnt = min(256, N_PTS - t);
        __syncthreads();
        if ((int)threadIdx.x < cnt) {
            int j = t + threadIdx.x;
            float rx = rpts[j*3+0], ry = rpts[j*3+1], rz = rpts[j*3+2];
            spts[threadIdx.x] = make_float4(rx, ry, rz, np_self_dot(rx, ry, rz));
        }
        __syncthreads();
        for (int k = 0; k < cnt; ++k) {
            float4 r = spts[k];
            float d = np_pair(sq, r.w, qx, qy, qz, r.x, r.y, r.z);
            if (d < best) { best = d; bidx = t + k; }
        }
    }
    if (q < N_PTS) {
        out[dir * N_PTS + q]       = best;
        out[(2 + dir) * N_PTS + q] = (float)bidx;
    }
}

extern "C" void kernel_launch(void* const* d_in, const int* in_sizes, int n_in,
                              void* d_out, int out_size, void* d_ws, size_t ws_size,
                              hipStream_t stream) {
    const float* preds = (const float*)d_in[0];  // [20000, 3]
    const float* gts   = (const float*)d_in[1];  // [1, 20000, 3]
    float* out = (float*)d_out;

    char* w = (char*)d_ws;
    size_t sorted_b = (size_t)2 * N_PTS * sizeof(float4);   // 640000
    size_t bstart_b = (size_t)2 * (NC + 1) * sizeof(int);   // 131080
    size_t cursor_b = (size_t)2 * NC * sizeof(int);         // 131072
    size_t need = sorted_b + bstart_b + cursor_b;

    if (ws_size >= need) {
        float4* sorted = (float4*)w;
        int* bstart = (int*)(w + sorted_b);
        int* cursor = (int*)(w + sorted_b + bstart_b);

        hipMemsetAsync(cursor, 0, cursor_b, stream);
        k_hist<<<(2 * N_PTS + 255) / 256, 256, 0, stream>>>(preds, gts, cursor);
        k_scan<<<2, 1024, 0, stream>>>(cursor, bstart);
        k_scatter<<<(2 * N_PTS + 255) / 256, 256, 0, stream>>>(
            preds, gts, cursor, sorted);
        k_main<<<2 * N_PTS / 16, 256, 0, stream>>>(sorted, bstart, out);
    } else {
        chamfer_direct_kernel<<<2 * QB79, 256, 0, stream>>>(preds, gts, out);
    }
}

// Round 2
// 161.834 us; speedup vs baseline: 1.4428x; 1.4428x over previous
//
#include <hip/hip_runtime.h>

#define N_PTS  20000
#define NG     128                  // grid NG x NG over [-6,6]^2
#define NC     (NG * NG)            // 16384 cells per cloud
#define GMIN   (-6.0f)
#define GINV   (NG / 12.0f)
#define MARGIN 5e-4f                // >> 2e-5 worst-case |P_np - d_true^2|
#define QB79   79                   // fallback

// ---- numpy-exact helpers (proven rounds 2/5/9/10/11/14) ----
__device__ __forceinline__ float np_self_dot(float x, float y, float z) {
    return __fadd_rn(__fadd_rn(__fmul_rn(x, x), __fmul_rn(y, y)),
                     __fmul_rn(z, z));
}
__device__ __forceinline__ unsigned ordmap(float f) {
    unsigned b = __float_as_uint(f);
    return (b & 0x80000000u) ? ~b : (b | 0x80000000u);
}
__device__ __forceinline__ float invord(unsigned h) {
    return __uint_as_float((h & 0x80000000u) ? (h ^ 0x80000000u) : ~h);
}
__device__ __forceinline__ int cellC(float v) {
    int c = (int)((v - GMIN) * GINV);
    return c < 0 ? 0 : (c > NG - 1 ? NG - 1 : c);
}
__device__ __forceinline__ unsigned long long wave_min_u64(unsigned long long k) {
    #pragma unroll
    for (int m = 1; m < 64; m <<= 1) {
        unsigned long long o = __shfl_xor(k, m, 64);
        k = (o < k) ? o : k;
    }
    return k;
}
__device__ __forceinline__ int imin2(int a, int b) { return a < b ? a : b; }
__device__ __forceinline__ int imax2(int a, int b) { return a > b ? a : b; }

// ---- build A1 (r16, kept): wide parallel histogram via global atomics ----
__global__ __launch_bounds__(256) void k_hist(
    const float* __restrict__ preds, const float* __restrict__ gts,
    int* __restrict__ cursor)
{
    int t = blockIdx.x * 256 + threadIdx.x;
    if (t >= 2 * N_PTS) return;
    int cl = t / N_PTS, i = t - cl * N_PTS;
    const float* src = cl ? gts : preds;
    int cell = cellC(src[i*3+0]) * NG + cellC(src[i*3+1]);
    atomicAdd(&cursor[cl * NC + cell], 1);
}

// ---- build A2 (r16, kept): scan-only, 1 block/cloud ----
__global__ __launch_bounds__(1024) void k_scan(
    int* __restrict__ cursor, int* __restrict__ bstart)
{
    __shared__ int psum[1024];      // 4 KB
    int cl = blockIdx.x, t = threadIdx.x;

    int base = t * 16;
    int v[16], s = 0;
    #pragma unroll
    for (int i = 0; i < 16; ++i) { v[i] = cursor[cl * NC + base + i]; s += v[i]; }
    psum[t] = s;
    __syncthreads();
    for (int off = 1; off < 1024; off <<= 1) {     // Hillis-Steele inclusive
        int a = (t >= off) ? psum[t - off] : 0;
        __syncthreads();
        psum[t] += a;
        __syncthreads();
    }
    int run = psum[t] - s;                          // exclusive prefix
    #pragma unroll
    for (int i = 0; i < 16; ++i) {
        bstart[cl * (NC + 1) + base + i] = run;
        cursor[cl * NC + base + i] = run;
        run += v[i];
    }
    if (t == 1023) bstart[cl * (NC + 1) + NC] = run;   // == N_PTS
}

// ---- build B (r15, kept): wide scatter into cell-sorted order ----
__global__ __launch_bounds__(256) void k_scatter(
    const float* __restrict__ preds, const float* __restrict__ gts,
    int* __restrict__ cursor, float4* __restrict__ sorted)
{
    int t = blockIdx.x * 256 + threadIdx.x;
    if (t >= 2 * N_PTS) return;
    int cl = t / N_PTS, i = t - cl * N_PTS;
    const float* src = cl ? gts : preds;
    float x = src[i*3+0], y = src[i*3+1], z = src[i*3+2];
    int cell = cellC(x) * NG + cellC(y);
    int pos = atomicAdd(&cursor[cl * NC + cell], 1);
    sorted[(size_t)cl * N_PTS + pos] = make_float4(x, y, z, __int_as_float(i));
}

// ---- main (r17): 4 consecutive cell-sorted queries per 64-lane wave,
// UNION window, wave-uniform control flow (r16's divergence lesson).
// Each lane evaluates its candidate against all 4 queries (sr shared).
// Numerics bit-identical to r9-r15: numpy-exact P; per-query key =
// (ordmap(P)<<32|idx); wave-min == numpy first-occurrence argmin;
// per-query W-boxes unioned => every query's certified box is inside the
// scanned box at termination; rescans idempotent.
__global__ __launch_bounds__(256) void k_main(
    const float4* __restrict__ sorted, const int* __restrict__ bstart,
    float* __restrict__ out)
{
    int wave  = blockIdx.x * 4 + ((int)threadIdx.x >> 6);  // 0..9999
    int lane  = threadIdx.x & 63;
    int qbase = wave * 4;                                  // 4 same-dir queries
    int dir   = qbase / N_PTS;
    int qpos  = qbase - dir * N_PTS;
    int rcl   = 1 - dir;

    const float4* rs = sorted + (size_t)rcl * N_PTS;
    const int*    cs = bstart + rcl * (NC + 1);
    const float4* qs = sorted + (size_t)dir * N_PTS + qpos;

    float4 q0 = qs[0], q1 = qs[1], q2 = qs[2], q3 = qs[3]; // broadcast loads
    float sq0 = np_self_dot(q0.x, q0.y, q0.z);
    float sq1 = np_self_dot(q1.x, q1.y, q1.z);
    float sq2 = np_self_dot(q2.x, q2.y, q2.z);
    float sq3 = np_self_dot(q3.x, q3.y, q3.z);

    unsigned long long k0 = ~0ULL, k1 = ~0ULL, k2 = ~0ULL, k3 = ~0ULL;

#define EVAL1(q, sq, kout)                                                 \
    {   float zz = __fadd_rn(__fadd_rn(__fmul_rn((q).x, rx),               \
                                       __fmul_rn((q).y, ry)),              \
                             __fmul_rn((q).z, rz));                        \
        float P  = __fsub_rn(__fadd_rn(sq, sr), __fadd_rn(zz, zz));        \
        unsigned long long kk =                                            \
            ((unsigned long long)ordmap(P) << 32) | ridx;                  \
        kout = (kk < kout) ? kk : kout; }

#define EVAL4(r)                                                           \
    {   float rx = (r).x, ry = (r).y, rz = (r).z;                          \
        float sr = np_self_dot(rx, ry, rz);                                \
        unsigned ridx = __float_as_uint((r).w);                            \
        EVAL1(q0, sq0, k0) EVAL1(q1, sq1, k1)                              \
        EVAL1(q2, sq2, k2) EVAL1(q3, sq3, k3) }

#define ROW(x, ya, yb)                                                     \
    if ((yb) >= (ya)) {                                                    \
        int lo = cs[(x) * NG + (ya)], hi = cs[(x) * NG + (yb) + 1];        \
        int p = lo + lane;                                                 \
        for (; p + 64 < hi; p += 128) {                                    \
            float4 r0 = rs[p];                                             \
            float4 r1 = rs[p + 64];        /* 2 loads in flight */         \
            EVAL4(r0) EVAL4(r1)                                            \
        }                                                                  \
        if (p < hi) { float4 r0 = rs[p]; EVAL4(r0) }                       \
    }

    int cx0 = cellC(q0.x), cy0 = cellC(q0.y);
    int cx1 = cellC(q1.x), cy1 = cellC(q1.y);
    int cx2 = cellC(q2.x), cy2 = cellC(q2.y);
    int cx3 = cellC(q3.x), cy3 = cellC(q3.y);
    int sxL = imax2(imin2(imin2(cx0, cx1), imin2(cx2, cx3)) - 1, 0);
    int sxR = imin2(imax2(imax2(cx0, cx1), imax2(cx2, cx3)) + 1, NG - 1);
    int syL = imax2(imin2(imin2(cy0, cy1), imin2(cy2, cy3)) - 1, 0);
    int syR = imin2(imax2(imax2(cy0, cy1), imax2(cy2, cy3)) + 1, NG - 1);

    for (int x = sxL; x <= sxR; ++x) ROW(x, syL, syR)      // seed union 3x3+

    for (int round = 0; round < 24; ++round) {
        k0 = wave_min_u64(k0); k1 = wave_min_u64(k1);
        k2 = wave_min_u64(k2); k3 = wave_min_u64(k3);
        int txL, txR, tyL, tyR;
        if (k0 != ~0ULL && k1 != ~0ULL && k2 != ~0ULL && k3 != ~0ULL) {
            float W0 = sqrtf(invord((unsigned)(k0 >> 32)) + MARGIN);
            float W1 = sqrtf(invord((unsigned)(k1 >> 32)) + MARGIN);
            float W2 = sqrtf(invord((unsigned)(k2 >> 32)) + MARGIN);
            float W3 = sqrtf(invord((unsigned)(k3 >> 32)) + MARGIN);
            txL = imin2(imin2(cellC(q0.x - W0), cellC(q1.x - W1)),
                        imin2(cellC(q2.x - W2), cellC(q3.x - W3)));
            txR = imax2(imax2(cellC(q0.x + W0), cellC(q1.x + W1)),
                        imax2(cellC(q2.x + W2), cellC(q3.x + W3)));
            tyL = imin2(imin2(cellC(q0.y - W0), cellC(q1.y - W1)),
                        imin2(cellC(q2.y - W2), cellC(q3.y - W3)));
            tyR = imax2(imax2(cellC(q0.y + W0), cellC(q1.y + W1)),
                        imax2(cellC(q2.y + W2), cellC(q3.y + W3)));
        } else {                                           // empty seed: grow
            int gx = sxR - sxL + 1, gy = syR - syL + 1;
            txL = sxL - gx; txR = sxR + gx;
            tyL = syL - gy; tyR = syR + gy;
            txL = txL < 0 ? 0 : txL;  tyL = tyL < 0 ? 0 : tyL;
            txR = txR > NG-1 ? NG-1 : txR;
            tyR = tyR > NG-1 ? NG-1 : tyR;
        }
        if (txL >= sxL && txR <= sxR && tyL >= syL && tyR <= syR) break;
        for (int x = txL; x <= txR; ++x) {
            if (x >= sxL && x <= sxR) {                    // new strips only
                ROW(x, tyL, syL - 1)
                ROW(x, syR + 1, tyR)
            } else {
                ROW(x, tyL, tyR)
            }
        }
        sxL = txL; sxR = txR; syL = tyL; syR = tyR;
    }
#undef ROW
#undef EVAL4
#undef EVAL1

    k0 = wave_min_u64(k0); k1 = wave_min_u64(k1);
    k2 = wave_min_u64(k2); k3 = wave_min_u64(k3);
    if (lane == 0) {
        int o0 = __float_as_int(q0.w), o1 = __float_as_int(q1.w);
        int o2 = __float_as_int(q2.w), o3 = __float_as_int(q3.w);
        out[dir * N_PTS + o0]       = invord((unsigned)(k0 >> 32));
        out[(2 + dir) * N_PTS + o0] = (float)(unsigned)(k0 & 0xFFFFFFFFu);
        out[dir * N_PTS + o1]       = invord((unsigned)(k1 >> 32));
        out[(2 + dir) * N_PTS + o1] = (float)(unsigned)(k1 & 0xFFFFFFFFu);
        out[dir * N_PTS + o2]       = invord((unsigned)(k2 >> 32));
        out[(2 + dir) * N_PTS + o2] = (float)(unsigned)(k2 & 0xFFFFFFFFu);
        out[dir * N_PTS + o3]       = invord((unsigned)(k3 >> 32));
        out[(2 + dir) * N_PTS + o3] = (float)(unsigned)(k3 & 0xFFFFFFFFu);
    }
}

// ---- fallback (tiny workspace): brute-force direct kernel (proven r2) ----
__device__ __forceinline__ float np_pair(float sq, float sr,
                                         float qx, float qy, float qz,
                                         float rx, float ry, float rz) {
    float zz = __fadd_rn(__fadd_rn(__fmul_rn(qx, rx), __fmul_rn(qy, ry)),
                         __fmul_rn(qz, rz));
    return __fsub_rn(__fadd_rn(sq, sr), __fadd_rn(zz, zz));
}

__global__ __launch_bounds__(256) void chamfer_direct_kernel(
    const float* __restrict__ preds, const float* __restrict__ gts,
    float* __restrict__ out)
{
    __shared__ float4 spts[256];
    int bid = blockIdx.x;
    int dir = bid / QB79;
    int qb  = bid - dir * QB79;
    int q   = qb * 256 + threadIdx.x;

    const float* qpts = (dir == 0) ? preds : gts;
    const float* rpts = (dir == 0) ? gts   : preds;

    int qc = (q < N_PTS) ? q : (N_PTS - 1);
    float qx = qpts[qc*3+0], qy = qpts[qc*3+1], qz = qpts[qc*3+2];
    float sq = np_self_dot(qx, qy, qz);
    float best = 3.4e38f;
    int   bidx = 0;

    for (int t = 0; t < N_PTS; t += 256) {
        int cnt = min(256, N_PTS - t);
        __syncthreads();
        if ((int)threadIdx.x < cnt) {
            int j = t + threadIdx.x;
            float rx = rpts[j*3+0], ry = rpts[j*3+1], rz = rpts[j*3+2];
            spts[threadIdx.x] = make_float4(rx, ry, rz, np_self_dot(rx, ry, rz));
        }
        __syncthreads();
        for (int k = 0; k < cnt; ++k) {
            float4 r = spts[k];
            float d = np_pair(sq, r.w, qx, qy, qz, r.x, r.y, r.z);
            if (d < best) { best = d; bidx = t + k; }
        }
    }
    if (q < N_PTS) {
        out[dir * N_PTS + q]       = best;
        out[(2 + dir) * N_PTS + q] = (float)bidx;
    }
}

extern "C" void kernel_launch(void* const* d_in, const int* in_sizes, int n_in,
                              void* d_out, int out_size, void* d_ws, size_t ws_size,
                              hipStream_t stream) {
    const float* preds = (const float*)d_in[0];  // [20000, 3]
    const float* gts   = (const float*)d_in[1];  // [1, 20000, 3]
    float* out = (float*)d_out;

    char* w = (char*)d_ws;
    size_t sorted_b = (size_t)2 * N_PTS * sizeof(float4);   // 640000
    size_t bstart_b = (size_t)2 * (NC + 1) * sizeof(int);   // 131080
    size_t cursor_b = (size_t)2 * NC * sizeof(int);         // 131072
    size_t need = sorted_b + bstart_b + cursor_b;

    if (ws_size >= need) {
        float4* sorted = (float4*)w;
        int* bstart = (int*)(w + sorted_b);
        int* cursor = (int*)(w + sorted_b + bstart_b);

        hipMemsetAsync(cursor, 0, cursor_b, stream);
        k_hist<<<(2 * N_PTS + 255) / 256, 256, 0, stream>>>(preds, gts, cursor);
        k_scan<<<2, 1024, 0, stream>>>(cursor, bstart);
        k_scatter<<<(2 * N_PTS + 255) / 256, 256, 0, stream>>>(
            preds, gts, cursor, sorted);
        k_main<<<2 * N_PTS / 16, 256, 0, stream>>>(sorted, bstart, out);
    } else {
        chamfer_direct_kernel<<<2 * QB79, 256, 0, stream>>>(preds, gts, out);
    }
}

// Round 3
// 126.417 us; speedup vs baseline: 1.8470x; 1.2802x over previous
//
#include <hip/hip_runtime.h>

#define N_PTS  20000
#define NG     128                  // grid NG x NG over [-6,6]^2
#define NC     (NG * NG)            // 16384 cells per cloud
#define GMIN   (-6.0f)
#define GINV   (NG / 12.0f)
#define MARGIN 5e-4f                // >> 2e-5 worst-case |P_np - d_true^2|
#define SSTRIDE (N_PTS / 64)        // 312; 63*312 = 19656 < 20000
#define QB79   79                   // fallback

// ---- numpy-exact helpers (proven rounds 2/5/9/10/11/14) ----
__device__ __forceinline__ float np_self_dot(float x, float y, float z) {
    return __fadd_rn(__fadd_rn(__fmul_rn(x, x), __fmul_rn(y, y)),
                     __fmul_rn(z, z));
}
__device__ __forceinline__ unsigned ordmap(float f) {
    unsigned b = __float_as_uint(f);
    return (b & 0x80000000u) ? ~b : (b | 0x80000000u);
}
__device__ __forceinline__ float invord(unsigned h) {
    return __uint_as_float((h & 0x80000000u) ? (h ^ 0x80000000u) : ~h);
}
__device__ __forceinline__ int cellC(float v) {
    int c = (int)((v - GMIN) * GINV);
    return c < 0 ? 0 : (c > NG - 1 ? NG - 1 : c);
}
__device__ __forceinline__ unsigned long long wave_min_u64(unsigned long long k) {
    #pragma unroll
    for (int m = 1; m < 64; m <<= 1) {
        unsigned long long o = __shfl_xor(k, m, 64);
        k = (o < k) ? o : k;
    }
    return k;
}
__device__ __forceinline__ int imin2(int a, int b) { return a < b ? a : b; }
__device__ __forceinline__ int imax2(int a, int b) { return a > b ? a : b; }

// ---- build A1 (r16, kept): wide parallel histogram via global atomics ----
__global__ __launch_bounds__(256) void k_hist(
    const float* __restrict__ preds, const float* __restrict__ gts,
    int* __restrict__ cursor)
{
    int t = blockIdx.x * 256 + threadIdx.x;
    if (t >= 2 * N_PTS) return;
    int cl = t / N_PTS, i = t - cl * N_PTS;
    const float* src = cl ? gts : preds;
    int cell = cellC(src[i*3+0]) * NG + cellC(src[i*3+1]);
    atomicAdd(&cursor[cl * NC + cell], 1);
}

// ---- build A2 (r16, kept): scan-only, 1 block/cloud ----
__global__ __launch_bounds__(1024) void k_scan(
    int* __restrict__ cursor, int* __restrict__ bstart)
{
    __shared__ int psum[1024];      // 4 KB
    int cl = blockIdx.x, t = threadIdx.x;

    int base = t * 16;
    int v[16], s = 0;
    #pragma unroll
    for (int i = 0; i < 16; ++i) { v[i] = cursor[cl * NC + base + i]; s += v[i]; }
    psum[t] = s;
    __syncthreads();
    for (int off = 1; off < 1024; off <<= 1) {     // Hillis-Steele inclusive
        int a = (t >= off) ? psum[t - off] : 0;
        __syncthreads();
        psum[t] += a;
        __syncthreads();
    }
    int run = psum[t] - s;                          // exclusive prefix
    #pragma unroll
    for (int i = 0; i < 16; ++i) {
        bstart[cl * (NC + 1) + base + i] = run;
        cursor[cl * NC + base + i] = run;
        run += v[i];
    }
    if (t == 1023) bstart[cl * (NC + 1) + NC] = run;   // == N_PTS
}

// ---- build B (r15, kept): wide scatter into cell-sorted order ----
__global__ __launch_bounds__(256) void k_scatter(
    const float* __restrict__ preds, const float* __restrict__ gts,
    int* __restrict__ cursor, float4* __restrict__ sorted)
{
    int t = blockIdx.x * 256 + threadIdx.x;
    if (t >= 2 * N_PTS) return;
    int cl = t / N_PTS, i = t - cl * N_PTS;
    const float* src = cl ? gts : preds;
    float x = src[i*3+0], y = src[i*3+1], z = src[i*3+2];
    int cell = cellC(x) * NG + cellC(y);
    int pos = atomicAdd(&cursor[cl * NC + cell], 1);
    sorted[(size_t)cl * N_PTS + pos] = make_float4(x, y, z, __int_as_float(i));
}

// ---- main (r18): 1 query per 64-lane wave (r0 shape), straight-line.
// Tail-kill design (r16/r17 post-mortems: k_main is tail-bound — serial
// bound-load chains on wide boxes + empty-seed growth rounds):
//  1. strided 64-sample gives a guaranteed upper bound in ONE load
//     (no empty-seed growth path left).
//  2. row bounds loaded lane-cooperatively (32 rows per scattered load,
//     shfl broadcast) — replaces R serial ~300cy loads with 1 load.
//  3. seed 3x3 + one W0-box scan certifies: refined W1 <= W0 so its box
//     is inside the scanned box; any unscanned point has
//     P > W0^2 = d_seed + MARGIN > d_final + numerics. No round loop.
// Numerics bit-identical to r9-r15: numpy-exact P; key=(ordmap(P)<<32|idx);
// wave-min == numpy first-occurrence argmin; samples/rescans are real
// candidates, idempotent under min.
__global__ __launch_bounds__(256) void k_main(
    const float4* __restrict__ sorted, const int* __restrict__ bstart,
    float* __restrict__ out)
{
    int wid  = blockIdx.x * 4 + ((int)threadIdx.x >> 6);   // 0..39999
    int lane = threadIdx.x & 63;
    int dir  = wid / N_PTS;
    int qpos = wid - dir * N_PTS;
    int rcl  = 1 - dir;

    const float4* rs = sorted + (size_t)rcl * N_PTS;
    const int*    cs = bstart + rcl * (NC + 1);

    float4 qv    = sorted[(size_t)dir * N_PTS + qpos];     // wave-broadcast
    int    origq = __float_as_int(qv.w);
    float qx = qv.x, qy = qv.y, qz = qv.z;
    float sq = np_self_dot(qx, qy, qz);

    unsigned long long key = ~0ULL;

#define EVAL(r)                                                            \
    {   float sr = np_self_dot((r).x, (r).y, (r).z);                       \
        float zz = __fadd_rn(__fadd_rn(__fmul_rn(qx, (r).x),               \
                                       __fmul_rn(qy, (r).y)),              \
                             __fmul_rn(qz, (r).z));                        \
        float P  = __fsub_rn(__fadd_rn(sq, sr), __fadd_rn(zz, zz));        \
        unsigned long long kk =                                            \
            ((unsigned long long)ordmap(P) << 32) | __float_as_uint((r).w);\
        key = (kk < key) ? kk : key; }

// Scan cells [xL..xR] x [yL..yR]. Bounds for 32 rows fetched in ONE
// scattered load: lanes 0..31 load row starts at column yL, lanes 32..63
// load row ends (start of column yR+1; ==(x+1)*NG start when yR==NG-1,
// and the NC sentinel closes the last row). Broadcast via shfl.
#define SCAN_BOX(xL, xR, yL, yR)                                           \
    for (int x0 = (xL); x0 <= (xR); x0 += 32) {                            \
        int nrows = imin2((xR) - x0 + 1, 32);                              \
        int xr  = imin2(x0 + (lane & 31), (xR));                           \
        int col = (lane < 32) ? (yL) : ((yR) + 1);                         \
        int bnd = cs[xr * NG + col];                                       \
        for (int rr = 0; rr < nrows; ++rr) {                               \
            int lo = __shfl(bnd, rr, 64);                                  \
            int hi = __shfl(bnd, 32 + rr, 64);                             \
            int p = lo + lane;                                             \
            for (; p + 64 < hi; p += 128) {                                \
                float4 r0 = rs[p];                                         \
                float4 r1 = rs[p + 64];        /* 2 loads in flight */     \
                EVAL(r0) EVAL(r1)                                          \
            }                                                              \
            if (p < hi) { float4 r0 = rs[p]; EVAL(r0) }                    \
        }                                                                  \
    }

    // phase 0: issue strided sample load (consumed after seed scan — ILP)
    float4 samp = rs[lane * SSTRIDE];

    // phase 1: seed 3x3 around the query cell
    int cx = cellC(qx), cy = cellC(qy);
    int sxL = cx > 0 ? cx - 1 : 0, sxR = cx < NG-1 ? cx + 1 : NG-1;
    int syL = cy > 0 ? cy - 1 : 0, syR = cy < NG-1 ? cy + 1 : NG-1;
    SCAN_BOX(sxL, sxR, syL, syR)
    EVAL(samp)                       // guaranteed-valid upper bound

    // phase 2: one certified W0-box scan (full rows; seed rescan is ~1 iter,
    // idempotent)
    key = wave_min_u64(key);
    float W = sqrtf(invord((unsigned)(key >> 32)) + MARGIN);
    int txL = cellC(qx - W), txR = cellC(qx + W);
    int tyL = cellC(qy - W), tyR = cellC(qy + W);
    if (!(txL >= sxL && txR <= sxR && tyL >= syL && tyR <= syR)) {
        SCAN_BOX(txL, txR, tyL, tyR)
        key = wave_min_u64(key);
    }
#undef SCAN_BOX
#undef EVAL

    if (lane == 0) {
        out[dir * N_PTS + origq]       = invord((unsigned)(key >> 32));
        out[(2 + dir) * N_PTS + origq] = (float)(unsigned)(key & 0xFFFFFFFFu);
    }
}

// ---- fallback (tiny workspace): brute-force direct kernel (proven r2) ----
__device__ __forceinline__ float np_pair(float sq, float sr,
                                         float qx, float qy, float qz,
                                         float rx, float ry, float rz) {
    float zz = __fadd_rn(__fadd_rn(__fmul_rn(qx, rx), __fmul_rn(qy, ry)),
                         __fmul_rn(qz, rz));
    return __fsub_rn(__fadd_rn(sq, sr), __fadd_rn(zz, zz));
}

__global__ __launch_bounds__(256) void chamfer_direct_kernel(
    const float* __restrict__ preds, const float* __restrict__ gts,
    float* __restrict__ out)
{
    __shared__ float4 spts[256];
    int bid = blockIdx.x;
    int dir = bid / QB79;
    int qb  = bid - dir * QB79;
    int q   = qb * 256 + threadIdx.x;

    const float* qpts = (dir == 0) ? preds : gts;
    const float* rpts = (dir == 0) ? gts   : preds;

    int qc = (q < N_PTS) ? q : (N_PTS - 1);
    float qx = qpts[qc*3+0], qy = qpts[qc*3+1], qz = qpts[qc*3+2];
    float sq = np_self_dot(qx, qy, qz);
    float best = 3.4e38f;
    int   bidx = 0;

    for (int t = 0; t < N_PTS; t += 256) {
        int cnt = min(256, N_PTS - t);
        __syncthreads();
        if ((int)threadIdx.x < cnt) {
            int j = t + threadIdx.x;
            float rx = rpts[j*3+0], ry = rpts[j*3+1], rz = rpts[j*3+2];
            spts[threadIdx.x] = make_float4(rx, ry, rz, np_self_dot(rx, ry, rz));
        }
        __syncthreads();
        for (int k = 0; k < cnt; ++k) {
            float4 r = spts[k];
            float d = np_pair(sq, r.w, qx, qy, qz, r.x, r.y, r.z);
            if (d < best) { best = d; bidx = t + k; }
        }
    }
    if (q < N_PTS) {
        out[dir * N_PTS + q]       = best;
        out[(2 + dir) * N_PTS + q] = (float)bidx;
    }
}

extern "C" void kernel_launch(void* const* d_in, const int* in_sizes, int n_in,
                              void* d_out, int out_size, void* d_ws, size_t ws_size,
                              hipStream_t stream) {
    const float* preds = (const float*)d_in[0];  // [20000, 3]
    const float* gts   = (const float*)d_in[1];  // [1, 20000, 3]
    float* out = (float*)d_out;

    char* w = (char*)d_ws;
    size_t sorted_b = (size_t)2 * N_PTS * sizeof(float4);   // 640000
    size_t bstart_b = (size_t)2 * (NC + 1) * sizeof(int);   // 131080
    size_t cursor_b = (size_t)2 * NC * sizeof(int);         // 131072
    size_t need = sorted_b + bstart_b + cursor_b;

    if (ws_size >= need) {
        float4* sorted = (float4*)w;
        int* bstart = (int*)(w + sorted_b);
        int* cursor = (int*)(w + sorted_b + bstart_b);

        hipMemsetAsync(cursor, 0, cursor_b, stream);
        k_hist<<<(2 * N_PTS + 255) / 256, 256, 0, stream>>>(preds, gts, cursor);
        k_scan<<<2, 1024, 0, stream>>>(cursor, bstart);
        k_scatter<<<(2 * N_PTS + 255) / 256, 256, 0, stream>>>(
            preds, gts, cursor, sorted);
        k_main<<<2 * N_PTS / 4, 256, 0, stream>>>(sorted, bstart, out);
    } else {
        chamfer_direct_kernel<<<2 * QB79, 256, 0, stream>>>(preds, gts, out);
    }
}

// Round 6
// 123.279 us; speedup vs baseline: 1.8940x; 1.0255x over previous
//
#include <hip/hip_runtime.h>

#define N_PTS  20000
#define NG     128                  // grid NG x NG over [-6,6]^2
#define NC     (NG * NG)            // 16384 cells per cloud
#define GMIN   (-6.0f)
#define GINV   (NG / 12.0f)
#define MARGIN 5e-4f                // >> 2e-5 worst-case |P_np - d_true^2|
#define SSTRIDE (N_PTS / 64)        // 312; 63*312 = 19656 < 20000
#define QB79   79                   // fallback

// ---- numpy-exact helpers (proven rounds 2/5/9/10/11/14) ----
__device__ __forceinline__ float np_self_dot(float x, float y, float z) {
    return __fadd_rn(__fadd_rn(__fmul_rn(x, x), __fmul_rn(y, y)),
                     __fmul_rn(z, z));
}
__device__ __forceinline__ unsigned ordmap(float f) {
    unsigned b = __float_as_uint(f);
    return (b & 0x80000000u) ? ~b : (b | 0x80000000u);
}
__device__ __forceinline__ float invord(unsigned h) {
    return __uint_as_float((h & 0x80000000u) ? (h ^ 0x80000000u) : ~h);
}
__device__ __forceinline__ int cellC(float v) {
    int c = (int)((v - GMIN) * GINV);
    return c < 0 ? 0 : (c > NG - 1 ? NG - 1 : c);
}
__device__ __forceinline__ unsigned long long wave_min_u64(unsigned long long k) {
    #pragma unroll
    for (int m = 1; m < 64; m <<= 1) {
        unsigned long long o = __shfl_xor(k, m, 64);
        k = (o < k) ? o : k;
    }
    return k;
}
__device__ __forceinline__ int imin2(int a, int b) { return a < b ? a : b; }

// ---- build A1 (r16/r18, PROVEN): wide parallel histogram, global atomics ----
__global__ __launch_bounds__(256) void k_hist(
    const float* __restrict__ preds, const float* __restrict__ gts,
    int* __restrict__ cursor)
{
    int t = blockIdx.x * 256 + threadIdx.x;
    if (t >= 2 * N_PTS) return;
    int cl = t / N_PTS, i = t - cl * N_PTS;
    const float* src = cl ? gts : preds;
    int cell = cellC(src[i*3+0]) * NG + cellC(src[i*3+1]);
    atomicAdd(&cursor[cl * NC + cell], 1);
}

// ---- build A2 (r16/r18, PROVEN): scan-only, 1 block/cloud ----
__global__ __launch_bounds__(1024) void k_scan(
    int* __restrict__ cursor, int* __restrict__ bstart)
{
    __shared__ int psum[1024];      // 4 KB
    int cl = blockIdx.x, t = threadIdx.x;

    int base = t * 16;
    int v[16], s = 0;
    #pragma unroll
    for (int i = 0; i < 16; ++i) { v[i] = cursor[cl * NC + base + i]; s += v[i]; }
    psum[t] = s;
    __syncthreads();
    for (int off = 1; off < 1024; off <<= 1) {     // Hillis-Steele inclusive
        int a = (t >= off) ? psum[t - off] : 0;
        __syncthreads();
        psum[t] += a;
        __syncthreads();
    }
    int run = psum[t] - s;                          // exclusive prefix
    #pragma unroll
    for (int i = 0; i < 16; ++i) {
        bstart[cl * (NC + 1) + base + i] = run;
        cursor[cl * NC + base + i] = run;
        run += v[i];
    }
    if (t == 1023) bstart[cl * (NC + 1) + NC] = run;   // == N_PTS
}

// ---- build B (r15/r18, PROVEN): wide scatter into cell-sorted order ----
__global__ __launch_bounds__(256) void k_scatter(
    const float* __restrict__ preds, const float* __restrict__ gts,
    int* __restrict__ cursor, float4* __restrict__ sorted)
{
    int t = blockIdx.x * 256 + threadIdx.x;
    if (t >= 2 * N_PTS) return;
    int cl = t / N_PTS, i = t - cl * N_PTS;
    const float* src = cl ? gts : preds;
    float x = src[i*3+0], y = src[i*3+1], z = src[i*3+2];
    int cell = cellC(x) * NG + cellC(y);
    int pos = atomicAdd(&cursor[cl * NC + cell], 1);
    sorted[(size_t)cl * N_PTS + pos] = make_float4(x, y, z, __int_as_float(i));
}

// ---- main (r21): EXACT r18 k_main algorithm (last passing, rowwise
// SCAN_BOX — the r19/r20 flattened scan_box failed correctness twice with
// identical signature and is reverted/banned until proven offline), with
// ONE launch-geometry change: 1 wave per block (64 threads, 40000 blocks).
// r18 counters showed VGPR=32/LDS=0 (no resource limit) yet 30% occupancy:
// 256-thread blocks hold 4 wave slots until their SLOWEST query finishes,
// and cell-sorted ordering clusters expensive queries into the same block.
// 1-wave blocks retire independently => scheduler backfills, tail shrinks.
// Numerics bit-identical: numpy-exact P; key=(ordmap(P)<<32|idx);
// wave-min == numpy first-occurrence argmin; samp EVAL guarantees a valid
// upper bound (no empty-seed path); W0-box certificate: refined W1 <= W0
// so its box is inside the scanned box; any unscanned point has
// P > W0^2 = d_seed + MARGIN > d_final + numerics; rescans idempotent.
__global__ __launch_bounds__(64) void k_main(
    const float4* __restrict__ sorted, const int* __restrict__ bstart,
    float* __restrict__ out)
{
    int wid  = blockIdx.x;                                 // 0..39999
    int lane = threadIdx.x;                                // 0..63
    int dir  = wid / N_PTS;
    int qpos = wid - dir * N_PTS;
    int rcl  = 1 - dir;

    const float4* rs = sorted + (size_t)rcl * N_PTS;
    const int*    cs = bstart + rcl * (NC + 1);

    float4 qv    = sorted[(size_t)dir * N_PTS + qpos];     // wave-broadcast
    int    origq = __float_as_int(qv.w);
    float qx = qv.x, qy = qv.y, qz = qv.z;
    float sq = np_self_dot(qx, qy, qz);

    unsigned long long key = ~0ULL;

#define EVAL(r)                                                            \
    {   float sr = np_self_dot((r).x, (r).y, (r).z);                       \
        float zz = __fadd_rn(__fadd_rn(__fmul_rn(qx, (r).x),               \
                                       __fmul_rn(qy, (r).y)),              \
                             __fmul_rn(qz, (r).z));                        \
        float P  = __fsub_rn(__fadd_rn(sq, sr), __fadd_rn(zz, zz));        \
        unsigned long long kk =                                            \
            ((unsigned long long)ordmap(P) << 32) | __float_as_uint((r).w);\
        key = (kk < key) ? kk : key; }

// Scan cells [xL..xR] x [yL..yR]. Bounds for 32 rows fetched in ONE
// scattered load: lanes 0..31 load row starts at column yL, lanes 32..63
// load row ends (start of column yR+1; ==(x+1)*NG start when yR==NG-1,
// and the NC sentinel closes the last row). Broadcast via shfl.
#define SCAN_BOX(xL, xR, yL, yR)                                           \
    for (int x0 = (xL); x0 <= (xR); x0 += 32) {                            \
        int nrows = imin2((xR) - x0 + 1, 32);                              \
        int xr  = imin2(x0 + (lane & 31), (xR));                           \
        int col = (lane < 32) ? (yL) : ((yR) + 1);                         \
        int bnd = cs[xr * NG + col];                                       \
        for (int rr = 0; rr < nrows; ++rr) {                               \
            int lo = __shfl(bnd, rr, 64);                                  \
            int hi = __shfl(bnd, 32 + rr, 64);                             \
            int p = lo + lane;                                             \
            for (; p + 64 < hi; p += 128) {                                \
                float4 r0 = rs[p];                                         \
                float4 r1 = rs[p + 64];        /* 2 loads in flight */     \
                EVAL(r0) EVAL(r1)                                          \
            }                                                              \
            if (p < hi) { float4 r0 = rs[p]; EVAL(r0) }                    \
        }                                                                  \
    }

    // phase 0: issue strided sample load (consumed after seed scan — ILP)
    float4 samp = rs[lane * SSTRIDE];

    // phase 1: seed 3x3 around the query cell
    int cx = cellC(qx), cy = cellC(qy);
    int sxL = cx > 0 ? cx - 1 : 0, sxR = cx < NG-1 ? cx + 1 : NG-1;
    int syL = cy > 0 ? cy - 1 : 0, syR = cy < NG-1 ? cy + 1 : NG-1;
    SCAN_BOX(sxL, sxR, syL, syR)
    EVAL(samp)                       // guaranteed-valid upper bound

    // phase 2: one certified W0-box scan (full rows; seed rescan is ~1 iter,
    // idempotent)
    key = wave_min_u64(key);
    float W = sqrtf(invord((unsigned)(key >> 32)) + MARGIN);
    int txL = cellC(qx - W), txR = cellC(qx + W);
    int tyL = cellC(qy - W), tyR = cellC(qy + W);
    if (!(txL >= sxL && txR <= sxR && tyL >= syL && tyR <= syR)) {
        SCAN_BOX(txL, txR, tyL, tyR)
        key = wave_min_u64(key);
    }
#undef SCAN_BOX
#undef EVAL

    if (lane == 0) {
        out[dir * N_PTS + origq]       = invord((unsigned)(key >> 32));
        out[(2 + dir) * N_PTS + origq] = (float)(unsigned)(key & 0xFFFFFFFFu);
    }
}

// ---- fallback (tiny workspace): brute-force direct kernel (proven r2) ----
__device__ __forceinline__ float np_pair(float sq, float sr,
                                         float qx, float qy, float qz,
                                         float rx, float ry, float rz) {
    float zz = __fadd_rn(__fadd_rn(__fmul_rn(qx, rx), __fmul_rn(qy, ry)),
                         __fmul_rn(qz, rz));
    return __fsub_rn(__fadd_rn(sq, sr), __fadd_rn(zz, zz));
}

__global__ __launch_bounds__(256) void chamfer_direct_kernel(
    const float* __restrict__ preds, const float* __restrict__ gts,
    float* __restrict__ out)
{
    __shared__ float4 spts[256];
    int bid = blockIdx.x;
    int dir = bid / QB79;
    int qb  = bid - dir * QB79;
    int q   = qb * 256 + threadIdx.x;

    const float* qpts = (dir == 0) ? preds : gts;
    const float* rpts = (dir == 0) ? gts   : preds;

    int qc = (q < N_PTS) ? q : (N_PTS - 1);
    float qx = qpts[qc*3+0], qy = qpts[qc*3+1], qz = qpts[qc*3+2];
    float sq = np_self_dot(qx, qy, qz);
    float best = 3.4e38f;
    int   bidx = 0;

    for (int t = 0; t < N_PTS; t += 256) {
        int cnt = min(256, N_PTS - t);
        __syncthreads();
        if ((int)threadIdx.x < cnt) {
            int j = t + threadIdx.x;
            float rx = rpts[j*3+0], ry = rpts[j*3+1], rz = rpts[j*3+2];
            spts[threadIdx.x] = make_float4(rx, ry, rz, np_self_dot(rx, ry, rz));
        }
        __syncthreads();
        for (int k = 0; k < cnt; ++k) {
            float4 r = spts[k];
            float d = np_pair(sq, r.w, qx, qy, qz, r.x, r.y, r.z);
            if (d < best) { best = d; bidx = t + k; }
        }
    }
    if (q < N_PTS) {
        out[dir * N_PTS + q]       = best;
        out[(2 + dir) * N_PTS + q] = (float)bidx;
    }
}

extern "C" void kernel_launch(void* const* d_in, const int* in_sizes, int n_in,
                              void* d_out, int out_size, void* d_ws, size_t ws_size,
                              hipStream_t stream) {
    const float* preds = (const float*)d_in[0];  // [20000, 3]
    const float* gts   = (const float*)d_in[1];  // [1, 20000, 3]
    float* out = (float*)d_out;

    char* w = (char*)d_ws;
    size_t sorted_b = (size_t)2 * N_PTS * sizeof(float4);   // 640000
    size_t bstart_b = (size_t)2 * (NC + 1) * sizeof(int);   // 131080
    size_t cursor_b = (size_t)2 * NC * sizeof(int);         // 131072
    size_t need = sorted_b + bstart_b + cursor_b;

    if (ws_size >= need) {
        float4* sorted = (float4*)w;
        int* bstart = (int*)(w + sorted_b);
        int* cursor = (int*)(w + sorted_b + bstart_b);

        hipMemsetAsync(cursor, 0, cursor_b, stream);
        k_hist<<<(2 * N_PTS + 255) / 256, 256, 0, stream>>>(preds, gts, cursor);
        k_scan<<<2, 1024, 0, stream>>>(cursor, bstart);
        k_scatter<<<(2 * N_PTS + 255) / 256, 256, 0, stream>>>(
            preds, gts, cursor, sorted);
        k_main<<<2 * N_PTS, 64, 0, stream>>>(sorted, bstart, out);
    } else {
        chamfer_direct_kernel<<<2 * QB79, 256, 0, stream>>>(preds, gts, out);
    }
}